// Round 2
// baseline (718.792 us; speedup 1.0000x reference)
//
#include <hip/hip_runtime.h>

// AttFusion R4: 2-pass cache-served re-read + high-occupancy deep-MLP loads.
//
// R3 post-mortem: register-resident x tile (192 VGPR at LEN=6) + bounds(256,2)
// -> LEN=6 path spilled, everything pinned at 2 waves/SIMD -> still
// latency-bound (~0.9 TB/s effective). Grid interleave was the only win (+9%).
//
// R4:
//  * only q (record 0, 32 VGPR) stays resident; pass 2 re-reads records
//    1..LEN-1 from L3 (concurrent footprint ~200 MB < 256 MB L3).
//  * __launch_bounds__(256,4): <=128 VGPR -> 4 waves/SIMD, 4 blocks/CU.
//    Pass-1 loads batched 8-wide per record -> deep, independent MLP.
//  * nontemporal stores: keep the 113 MB output from evicting x in L3
//    between pass 1 and pass 2.
//  * grid unchanged from R3: 3456 blocks, batch-interleaved (b = bid % B).

#define CC 256
#define PP (96 * 288)      // 27648 pixels
#define P4 (PP / 4)        // 6912 float4 per (record,channel) row
#define LMAXC 6
#define TPX 8              // float4-pixels per block tile
#define NGRP 32            // channel groups (8 channels each)

typedef float f32x4 __attribute__((ext_vector_type(4)));

template <int LEN>
__device__ __forceinline__ void att_body(
    const float4* __restrict__ xbase,   // x + off*CP4 + c0*P4 + tile*TPX + pxl
    float4* __restrict__ obase,
    float4 (&red)[LMAXC][NGRP][TPX],
    float4 (&sc)[LMAXC][TPX],
    float4 (&att)[LMAXC][TPX],
    int pxl, int grp, int tid)
{
    const size_t CP4 = (size_t)CC * P4;

    // ---- q tile: resident for the whole body (32 VGPR) ----
    float4 x0[8];
#pragma unroll
    for (int ci = 0; ci < 8; ++ci) x0[ci] = xbase[(size_t)ci * P4];

    // ---- Pass 1: scores. record-major, 8 loads batched per record ----
    float4 s[LEN];
    {
        float4 a = make_float4(0.f, 0.f, 0.f, 0.f);
#pragma unroll
        for (int ci = 0; ci < 8; ++ci) {
            a.x = fmaf(x0[ci].x, x0[ci].x, a.x);
            a.y = fmaf(x0[ci].y, x0[ci].y, a.y);
            a.z = fmaf(x0[ci].z, x0[ci].z, a.z);
            a.w = fmaf(x0[ci].w, x0[ci].w, a.w);
        }
        s[0] = a;
    }
#pragma unroll
    for (int l = 1; l < LEN; ++l) {
        float4 xl[8];
#pragma unroll
        for (int ci = 0; ci < 8; ++ci)
            xl[ci] = xbase[(size_t)l * CP4 + (size_t)ci * P4];
        float4 a = make_float4(0.f, 0.f, 0.f, 0.f);
#pragma unroll
        for (int ci = 0; ci < 8; ++ci) {
            a.x = fmaf(x0[ci].x, xl[ci].x, a.x);
            a.y = fmaf(x0[ci].y, xl[ci].y, a.y);
            a.z = fmaf(x0[ci].z, xl[ci].z, a.z);
            a.w = fmaf(x0[ci].w, xl[ci].w, a.w);
        }
        s[l] = a;
    }

#pragma unroll
    for (int l = 0; l < LEN; ++l) red[l][grp][pxl] = s[l];
    __syncthreads();

    // ---- Reduce over the 32 channel groups: one thread per (l, px) ----
    if (tid < 8 * LEN) {
        const int l = tid >> 3, px = tid & 7;
        float4 a = make_float4(0.f, 0.f, 0.f, 0.f);
#pragma unroll
        for (int g = 0; g < NGRP; ++g) {
            const float4 r = red[l][g][px];
            a.x += r.x; a.y += r.y; a.z += r.z; a.w += r.w;
        }
        // scale = 1/sqrt(256)
        sc[l][px] = make_float4(a.x * 0.0625f, a.y * 0.0625f,
                                a.z * 0.0625f, a.w * 0.0625f);
    }
    __syncthreads();

    // ---- Softmax over l: one thread per px4 ----
    if (tid < TPX) {
        float4 v[LEN];
#pragma unroll
        for (int l = 0; l < LEN; ++l) v[l] = sc[l][tid];
        float4 m = v[0];
#pragma unroll
        for (int l = 1; l < LEN; ++l) {
            m.x = fmaxf(m.x, v[l].x); m.y = fmaxf(m.y, v[l].y);
            m.z = fmaxf(m.z, v[l].z); m.w = fmaxf(m.w, v[l].w);
        }
        float4 sum = make_float4(0.f, 0.f, 0.f, 0.f);
#pragma unroll
        for (int l = 0; l < LEN; ++l) {
            v[l].x = __expf(v[l].x - m.x); sum.x += v[l].x;
            v[l].y = __expf(v[l].y - m.y); sum.y += v[l].y;
            v[l].z = __expf(v[l].z - m.z); sum.z += v[l].z;
            v[l].w = __expf(v[l].w - m.w); sum.w += v[l].w;
        }
        const float4 inv = make_float4(1.f / sum.x, 1.f / sum.y,
                                       1.f / sum.z, 1.f / sum.w);
#pragma unroll
        for (int l = 0; l < LEN; ++l)
            att[l][tid] = make_float4(v[l].x * inv.x, v[l].y * inv.y,
                                      v[l].z * inv.z, v[l].w * inv.w);
    }
    __syncthreads();

    // ---- Pass 2: q from registers, records 1..LEN-1 re-read (L3-served) ----
    float4 a[LEN];
#pragma unroll
    for (int l = 0; l < LEN; ++l) a[l] = att[l][pxl];

#pragma unroll 2
    for (int ci = 0; ci < 8; ++ci) {
        float4 xl[LEN > 1 ? LEN - 1 : 1];
#pragma unroll
        for (int l = 1; l < LEN; ++l)
            xl[l - 1] = xbase[(size_t)l * CP4 + (size_t)ci * P4];

        float4 acc;
        acc.x = a[0].x * x0[ci].x;
        acc.y = a[0].y * x0[ci].y;
        acc.z = a[0].z * x0[ci].z;
        acc.w = a[0].w * x0[ci].w;
#pragma unroll
        for (int l = 1; l < LEN; ++l) {
            acc.x = fmaf(a[l].x, xl[l - 1].x, acc.x);
            acc.y = fmaf(a[l].y, xl[l - 1].y, acc.y);
            acc.z = fmaf(a[l].z, xl[l - 1].z, acc.z);
            acc.w = fmaf(a[l].w, xl[l - 1].w, acc.w);
        }
        // nontemporal store: don't let output evict x from L3
        __builtin_nontemporal_store(*(const f32x4*)&acc,
                                    (f32x4*)&obase[(size_t)ci * P4]);
    }
}

__global__ __launch_bounds__(256, 4) void attfusion_kernel(
    const float4* __restrict__ x, const int* __restrict__ rl,
    float4* __restrict__ out, int B)
{
    __shared__ float4 red[LMAXC][NGRP][TPX];
    __shared__ float4 sc[LMAXC][TPX];
    __shared__ float4 att[LMAXC][TPX];

    const int tid = threadIdx.x;
    const int pxl = tid & 7;          // float4-pixel within tile
    const int grp = tid >> 3;         // channel group 0..31 (8 ch each)

    const unsigned bid = blockIdx.x;
    const int b    = bid % (unsigned)B;   // interleave batches in dispatch order
    const int tile = bid / (unsigned)B;

    int off = 0;
    for (int i = 0; i < b; ++i) off += rl[i];
    int len = rl[b];
    if (len > LMAXC) len = LMAXC;
    if (len < 1)     len = 1;

    const size_t CP4 = (size_t)CC * P4;
    const int c0 = grp * 8;
    const float4* xbase = x   + (size_t)off * CP4 + (size_t)c0 * P4
                              + (size_t)tile * TPX + pxl;
    float4*       obase = out + (size_t)b   * CP4 + (size_t)c0 * P4
                              + (size_t)tile * TPX + pxl;

    switch (len) {
        case 1: att_body<1>(xbase, obase, red, sc, att, pxl, grp, tid); break;
        case 2: att_body<2>(xbase, obase, red, sc, att, pxl, grp, tid); break;
        case 3: att_body<3>(xbase, obase, red, sc, att, pxl, grp, tid); break;
        case 4: att_body<4>(xbase, obase, red, sc, att, pxl, grp, tid); break;
        case 5: att_body<5>(xbase, obase, red, sc, att, pxl, grp, tid); break;
        default: att_body<6>(xbase, obase, red, sc, att, pxl, grp, tid); break;
    }
}

extern "C" void kernel_launch(void* const* d_in, const int* in_sizes, int n_in,
                              void* d_out, int out_size, void* d_ws, size_t ws_size,
                              hipStream_t stream) {
    const float4* x   = (const float4*)d_in[0];
    const int*    rl  = (const int*)d_in[1];
    float4*       out = (float4*)d_out;
    const int B = in_sizes[1];                 // 4
    dim3 grid((P4 / TPX) * B);                 // 864 tiles x 4 batches = 3456
    attfusion_kernel<<<grid, 256, 0, stream>>>(x, rl, out, B);
}

// Round 3
// 659.607 us; speedup vs baseline: 1.0897x; 1.0897x over previous
//
#include <hip/hip_runtime.h>

// AttFusion R5: R3 structure (register-resident, read-once) with the LEN>=5
// spill fixed by hybrid residency + single-barrier wave-parallel softmax.
//
// History: R2 (2-pass re-read) 711us; R3 (full register residency) 644us;
// R4 (q-only + re-read + NT stores) 719us -> re-read on the block tail is
// harmful, NT stores suspect. R3's defect: LEN=6 needs ~260 VGPR > 256 cap
// -> len-6 batch (864 blocks, critical path) spilled.
//
// R5:
//  * records 0..3 register-resident (<=128 VGPR data, ~200 peak, no spill
//    at __launch_bounds__(256,2)); records 4..5 streamed in pass 1 and
//    re-read (only those, ~85 MB, L3-served) in pass 2. LEN<=4 == R3.
//  * softmax: one wave does LDS g-reduce then butterfly __shfl_xor over
//    the l-dimension (masks 8/16/32, pad lanes with -1e9) -> one fewer
//    barrier, 64 active lanes instead of 8.
//  * plain stores (NT removed). Grid unchanged: 3456 blocks, b = bid % B.

#define CC 256
#define PP (96 * 288)      // 27648 pixels
#define P4 (PP / 4)        // 6912 float4 per (record,channel) row
#define LMAXC 6
#define TPX 8              // float4-pixels per block tile
#define NGRP 32            // channel groups (8 channels each)
#define LSTRIDE 257        // float4 stride per l-plane in LDS (de-aligns banks)

__device__ __forceinline__ float4 shfl_xor4(float4 v, int mask) {
    return make_float4(__shfl_xor(v.x, mask), __shfl_xor(v.y, mask),
                       __shfl_xor(v.z, mask), __shfl_xor(v.w, mask));
}

template <int LEN>
__device__ __forceinline__ void att_body(
    const float4* __restrict__ xbase,   // x + off*CP4 + c0*P4 + tile*TPX + pxl
    float4* __restrict__ obase,
    float4* __restrict__ red,           // [LMAXC * LSTRIDE]
    float4 (&att)[LMAXC][TPX],
    int pxl, int grp, int tid)
{
    constexpr int RES = (LEN < 4) ? LEN : 4;   // resident records
    const size_t CP4 = (size_t)CC * P4;

    // ---- Pass 1a: resident records 0..RES-1 into registers ----
    float4 xd[RES][8];
#pragma unroll
    for (int ci = 0; ci < 8; ++ci)
#pragma unroll
        for (int l = 0; l < RES; ++l)
            xd[l][ci] = xbase[(size_t)l * CP4 + (size_t)ci * P4];

    float4 s[LEN];
    {   // q . q
        float4 a = make_float4(0.f, 0.f, 0.f, 0.f);
#pragma unroll
        for (int ci = 0; ci < 8; ++ci) {
            a.x = fmaf(xd[0][ci].x, xd[0][ci].x, a.x);
            a.y = fmaf(xd[0][ci].y, xd[0][ci].y, a.y);
            a.z = fmaf(xd[0][ci].z, xd[0][ci].z, a.z);
            a.w = fmaf(xd[0][ci].w, xd[0][ci].w, a.w);
        }
        s[0] = a;
    }
#pragma unroll
    for (int l = 1; l < RES; ++l) {
        float4 a = make_float4(0.f, 0.f, 0.f, 0.f);
#pragma unroll
        for (int ci = 0; ci < 8; ++ci) {
            a.x = fmaf(xd[0][ci].x, xd[l][ci].x, a.x);
            a.y = fmaf(xd[0][ci].y, xd[l][ci].y, a.y);
            a.z = fmaf(xd[0][ci].z, xd[l][ci].z, a.z);
            a.w = fmaf(xd[0][ci].w, xd[l][ci].w, a.w);
        }
        s[l] = a;
    }
    // ---- Pass 1b: streamed records RES..LEN-1 ----
#pragma unroll
    for (int l = RES; l < LEN; ++l) {
        float4 xl[8];
#pragma unroll
        for (int ci = 0; ci < 8; ++ci)
            xl[ci] = xbase[(size_t)l * CP4 + (size_t)ci * P4];
        float4 a = make_float4(0.f, 0.f, 0.f, 0.f);
#pragma unroll
        for (int ci = 0; ci < 8; ++ci) {
            a.x = fmaf(xd[0][ci].x, xl[ci].x, a.x);
            a.y = fmaf(xd[0][ci].y, xl[ci].y, a.y);
            a.z = fmaf(xd[0][ci].z, xl[ci].z, a.z);
            a.w = fmaf(xd[0][ci].w, xl[ci].w, a.w);
        }
        s[l] = a;
    }

#pragma unroll
    for (int l = 0; l < LEN; ++l) red[l * LSTRIDE + tid] = s[l];
    __syncthreads();

    // ---- Reduce + softmax: one wave, lane = (l, px), butterfly over l ----
    if (tid < 64) {
        const int l = tid >> 3, px = tid & 7;
        float4 v;
        if (l < LEN) {
            float4 a = make_float4(0.f, 0.f, 0.f, 0.f);
#pragma unroll
            for (int g = 0; g < NGRP; ++g) {
                const float4 r = red[l * LSTRIDE + g * 8 + px];
                a.x += r.x; a.y += r.y; a.z += r.z; a.w += r.w;
            }
            // scale = 1/sqrt(256)
            v = make_float4(a.x * 0.0625f, a.y * 0.0625f,
                            a.z * 0.0625f, a.w * 0.0625f);
        } else {
            v = make_float4(-1e9f, -1e9f, -1e9f, -1e9f);
        }
        float4 m = v;
#pragma unroll
        for (int mask = 8; mask <= 32; mask <<= 1) {
            const float4 o = shfl_xor4(m, mask);
            m.x = fmaxf(m.x, o.x); m.y = fmaxf(m.y, o.y);
            m.z = fmaxf(m.z, o.z); m.w = fmaxf(m.w, o.w);
        }
        float4 e;
        e.x = __expf(v.x - m.x); e.y = __expf(v.y - m.y);
        e.z = __expf(v.z - m.z); e.w = __expf(v.w - m.w);
        float4 sum = e;
#pragma unroll
        for (int mask = 8; mask <= 32; mask <<= 1) {
            const float4 o = shfl_xor4(sum, mask);
            sum.x += o.x; sum.y += o.y; sum.z += o.z; sum.w += o.w;
        }
        if (l < LEN)
            att[l][px] = make_float4(e.x / sum.x, e.y / sum.y,
                                     e.z / sum.z, e.w / sum.w);
    }
    __syncthreads();

    // ---- Pass 2: residents from registers, tail records re-read (L3) ----
    float4 a[LEN];
#pragma unroll
    for (int l = 0; l < LEN; ++l) a[l] = att[l][pxl];

#pragma unroll
    for (int ci = 0; ci < 8; ++ci) {
        float4 acc;
        acc.x = a[0].x * xd[0][ci].x;
        acc.y = a[0].y * xd[0][ci].y;
        acc.z = a[0].z * xd[0][ci].z;
        acc.w = a[0].w * xd[0][ci].w;
#pragma unroll
        for (int l = 1; l < RES; ++l) {
            acc.x = fmaf(a[l].x, xd[l][ci].x, acc.x);
            acc.y = fmaf(a[l].y, xd[l][ci].y, acc.y);
            acc.z = fmaf(a[l].z, xd[l][ci].z, acc.z);
            acc.w = fmaf(a[l].w, xd[l][ci].w, acc.w);
        }
#pragma unroll
        for (int l = RES; l < LEN; ++l) {
            const float4 xl = xbase[(size_t)l * CP4 + (size_t)ci * P4];
            acc.x = fmaf(a[l].x, xl.x, acc.x);
            acc.y = fmaf(a[l].y, xl.y, acc.y);
            acc.z = fmaf(a[l].z, xl.z, acc.z);
            acc.w = fmaf(a[l].w, xl.w, acc.w);
        }
        obase[(size_t)ci * P4] = acc;
    }
}

__global__ __launch_bounds__(256, 2) void attfusion_kernel(
    const float4* __restrict__ x, const int* __restrict__ rl,
    float4* __restrict__ out, int B)
{
    __shared__ float4 red[LMAXC * LSTRIDE];
    __shared__ float4 att[LMAXC][TPX];

    const int tid = threadIdx.x;
    const int pxl = tid & 7;          // float4-pixel within tile
    const int grp = tid >> 3;         // channel group 0..31 (8 ch each)

    const unsigned bid = blockIdx.x;
    const int b    = bid % (unsigned)B;   // interleave batches in dispatch order
    const int tile = bid / (unsigned)B;

    int off = 0;
    for (int i = 0; i < b; ++i) off += rl[i];
    int len = rl[b];
    if (len > LMAXC) len = LMAXC;
    if (len < 1)     len = 1;

    const size_t CP4 = (size_t)CC * P4;
    const int c0 = grp * 8;
    const float4* xbase = x   + (size_t)off * CP4 + (size_t)c0 * P4
                              + (size_t)tile * TPX + pxl;
    float4*       obase = out + (size_t)b   * CP4 + (size_t)c0 * P4
                              + (size_t)tile * TPX + pxl;

    switch (len) {
        case 1: att_body<1>(xbase, obase, red, att, pxl, grp, tid); break;
        case 2: att_body<2>(xbase, obase, red, att, pxl, grp, tid); break;
        case 3: att_body<3>(xbase, obase, red, att, pxl, grp, tid); break;
        case 4: att_body<4>(xbase, obase, red, att, pxl, grp, tid); break;
        case 5: att_body<5>(xbase, obase, red, att, pxl, grp, tid); break;
        default: att_body<6>(xbase, obase, red, att, pxl, grp, tid); break;
    }
}

extern "C" void kernel_launch(void* const* d_in, const int* in_sizes, int n_in,
                              void* d_out, int out_size, void* d_ws, size_t ws_size,
                              hipStream_t stream) {
    const float4* x   = (const float4*)d_in[0];
    const int*    rl  = (const int*)d_in[1];
    float4*       out = (float4*)d_out;
    const int B = in_sizes[1];                 // 4
    dim3 grid((P4 / TPX) * B);                 // 864 tiles x 4 batches = 3456
    attfusion_kernel<<<grid, 256, 0, stream>>>(x, rl, out, B);
}